// Round 4
// baseline (1380.542 us; speedup 1.0000x reference)
//
#include <hip/hip_runtime.h>
#include <hip/hip_bf16.h>
#include <stdint.h>

// Top-2 MoE router: s=8192 tokens, e=8 experts, capacity=2560.
// out = cb_weight[s][8][cap] f32 ++ sec_mask[s][8][cap] f32(0/1)  = 1.342 GB.
// Memory-bound: dominated by zero-fill writes. Strategy:
//   K1 router (1 block): softmax+top2+token-order rank scan -> table[s]={pos1,w1,pos2,w2}
//   K2 fill: linear grid-stride zero sweep (same pattern as rocclr fillBuffer, 6.2 TB/s)
//   K3 scatter: <=4 scattered dword stores per token.

#define ST 1024     // scan threads
#define ROUNDS 8    // ST*ROUNDS = 8192 tokens

__global__ __launch_bounds__(ST) void router_kernel(
    const float* __restrict__ in, float4* __restrict__ table, int s, int cap) {
  __shared__ int wc1[ST / 64][8], wc2[ST / 64][8];
  __shared__ int base1[8], base2[8];
  const int tid = threadIdx.x;
  const int lane = tid & 63;
  const int wave = tid >> 6;
  const unsigned long long lt = (lane == 0) ? 0ULL : (~0ULL >> (64 - lane));

  if (tid < 8) { base1[tid] = 0; base2[tid] = 0; }
  __syncthreads();

  int e1a[ROUNDS], e2a[ROUNDS], r1a[ROUNDS], r2a[ROUNDS];
  float w1a[ROUNDS], w2a[ROUNDS];

#pragma unroll
  for (int k = 0; k < ROUNDS; ++k) {
    const int t = k * ST + tid;
    int e1 = -1, e2 = -1;
    float w1 = 0.f, w2 = 0.f;
    if (t < s) {
      const float4* p = reinterpret_cast<const float4*>(in + (size_t)t * 8);
      const float4 a = p[0], b = p[1];
      float v[8] = {a.x, a.y, a.z, a.w, b.x, b.y, b.z, b.w};
      float m = v[0];
#pragma unroll
      for (int i = 1; i < 8; ++i) m = fmaxf(m, v[i]);
      float ex[8], sum = 0.f;
#pragma unroll
      for (int i = 0; i < 8; ++i) { ex[i] = expf(v[i] - m); sum += ex[i]; }
      const float inv = 1.0f / sum;
      // argmax, first-occurrence tie-break (strict >)
      e1 = 0; float b1 = v[0];
#pragma unroll
      for (int i = 1; i < 8; ++i) { if (v[i] > b1) { b1 = v[i]; e1 = i; } }
      float b2 = -1e38f; e2 = 0;
#pragma unroll
      for (int i = 0; i < 8; ++i) {
        if (i != e1 && v[i] > b2) { b2 = v[i]; e2 = i; }
      }
      w1 = ex[e1] * inv;
      w2 = ex[e2] * inv;
    }
    // token-order exclusive prefix rank within each expert, both masks at once
    int lp1 = 0, lp2 = 0;
#pragma unroll
    for (int e = 0; e < 8; ++e) {
      const unsigned long long m1 = __ballot(e1 == e);
      const unsigned long long m2 = __ballot(e2 == e);
      if (lane == 0) { wc1[wave][e] = __popcll(m1); wc2[wave][e] = __popcll(m2); }
      if (e1 == e) lp1 = __popcll(m1 & lt);
      if (e2 == e) lp2 = __popcll(m2 & lt);
    }
    __syncthreads();
    int r1 = 0, r2 = 0;
    if (t < s) {
      int wp1 = 0, wp2 = 0;
      for (int w = 0; w < wave; ++w) { wp1 += wc1[w][e1]; wp2 += wc2[w][e2]; }
      r1 = base1[e1] + wp1 + lp1;
      r2 = base2[e2] + wp2 + lp2;
    }
    __syncthreads();
    if (tid < 8) {
      int a1 = 0, a2 = 0;
      for (int w = 0; w < ST / 64; ++w) { a1 += wc1[w][tid]; a2 += wc2[w][tid]; }
      base1[tid] += a1;
      base2[tid] += a2;
    }
    __syncthreads();
    e1a[k] = e1; e2a[k] = e2; r1a[k] = r1; r2a[k] = r2; w1a[k] = w1; w2a[k] = w2;
  }

  // base1[e] == tot1[e] (pre-drop top-1 totals, as in the reference).
#pragma unroll
  for (int k = 0; k < ROUNDS; ++k) {
    const int t = k * ST + tid;
    if (t >= s) continue;
    const int p1 = (r1a[k] < cap) ? e1a[k] * cap + r1a[k] : -1;
    const int rr2 = r2a[k] + base1[e2a[k]];
    const int p2 = (rr2 < cap) ? e2a[k] * cap + rr2 : -1;
    float4 rec;
    rec.x = __int_as_float(p1);
    rec.y = w1a[k];
    rec.z = __int_as_float(p2);
    rec.w = w2a[k];
    table[t] = rec;
  }
}

// Pure linear zero sweep — same access pattern as rocclr fillBuffer (6.2 TB/s).
__global__ __launch_bounds__(256) void fill_kernel(float4* __restrict__ out,
                                                   unsigned n4) {
  unsigned i = blockIdx.x * 256u + threadIdx.x;
  const unsigned stride = gridDim.x * 256u;
  const float4 z = make_float4(0.f, 0.f, 0.f, 0.f);
  for (; i < n4; i += stride) out[i] = z;
}

__global__ __launch_bounds__(256) void scatter_kernel(
    const float4* __restrict__ table, float* __restrict__ out, int s, int row) {
  const int t = blockIdx.x * 256 + threadIdx.x;
  if (t >= s) return;
  const float4 rec = table[t];
  const int p1 = __float_as_int(rec.x);
  const int p2 = __float_as_int(rec.z);
  float* cb = out + (size_t)t * row;
  float* mk = cb + (size_t)s * row;
  if (p1 >= 0) { cb[p1] = rec.y; mk[p1] = (rec.y != 0.f) ? 1.f : 0.f; }
  if (p2 >= 0) { cb[p2] = rec.w; mk[p2] = (rec.w != 0.f) ? 1.f : 0.f; }
}

extern "C" void kernel_launch(void* const* d_in, const int* in_sizes, int n_in,
                              void* d_out, int out_size, void* d_ws, size_t ws_size,
                              hipStream_t stream) {
  const float* in = (const float*)d_in[0];
  const int E = 8;
  const int s = in_sizes[0] / E;  // 8192
  int cap = (int)((5LL * s) / (2LL * E));  // floor(2*1.25*s/e)
  cap += cap % 2;
  if (cap < 4) cap = 4;
  const int row = E * cap;  // 20480

  float4* table = (float4*)d_ws;  // s * 16B

  // K2 first: the big fill has no dependency on the router.
  const unsigned n4 = (unsigned)((size_t)out_size / 4);
  fill_kernel<<<2048, 256, 0, stream>>>((float4*)d_out, n4);
  router_kernel<<<1, ST, 0, stream>>>(in, table, s, cap);
  scatter_kernel<<<(s + 255) / 256, 256, 0, stream>>>(table, (float*)d_out, s, row);
}

// Round 5
// 1321.656 us; speedup vs baseline: 1.0446x; 1.0446x over previous
//
#include <hip/hip_runtime.h>
#include <hip/hip_bf16.h>
#include <stdint.h>

// Top-2 MoE router: s=8192 tokens, e=8 experts, capacity=2560.
// out = cb_weight[s][8][cap] f32 ++ sec_mask[s][8][cap] f32(0/1) = 1.342 GB.
// Strategy: router (1 block) -> table[s]={p1,w1,p2,w2}; then ONE linear pass
// over the output embedding the scattered values during the zero sweep
// (no separate scatter, no read-modify-write lines, no fill->scatter dep).

#define ST 1024     // scan threads
#define ROUNDS 8    // ST*ROUNDS = 8192 tokens

__global__ __launch_bounds__(ST) void router_kernel(
    const float* __restrict__ in, float4* __restrict__ table, int s, int cap) {
  __shared__ int wc1[ST / 64][8], wc2[ST / 64][8];
  __shared__ int base1[8], base2[8];
  const int tid = threadIdx.x;
  const int lane = tid & 63;
  const int wave = tid >> 6;
  const unsigned long long lt = (lane == 0) ? 0ULL : (~0ULL >> (64 - lane));

  if (tid < 8) { base1[tid] = 0; base2[tid] = 0; }
  __syncthreads();

  int e1a[ROUNDS], e2a[ROUNDS], r1a[ROUNDS], r2a[ROUNDS];
  float w1a[ROUNDS], w2a[ROUNDS];

#pragma unroll
  for (int k = 0; k < ROUNDS; ++k) {
    const int t = k * ST + tid;
    int e1 = -1, e2 = -1;
    float w1 = 0.f, w2 = 0.f;
    if (t < s) {
      const float4* p = reinterpret_cast<const float4*>(in + (size_t)t * 8);
      const float4 a = p[0], b = p[1];
      float v[8] = {a.x, a.y, a.z, a.w, b.x, b.y, b.z, b.w};
      float m = v[0];
#pragma unroll
      for (int i = 1; i < 8; ++i) m = fmaxf(m, v[i]);
      float ex[8], sum = 0.f;
#pragma unroll
      for (int i = 0; i < 8; ++i) { ex[i] = expf(v[i] - m); sum += ex[i]; }
      const float inv = 1.0f / sum;
      e1 = 0; float b1 = v[0];
#pragma unroll
      for (int i = 1; i < 8; ++i) { if (v[i] > b1) { b1 = v[i]; e1 = i; } }
      float b2 = -1e38f; e2 = 0;
#pragma unroll
      for (int i = 0; i < 8; ++i) {
        if (i != e1 && v[i] > b2) { b2 = v[i]; e2 = i; }
      }
      w1 = ex[e1] * inv;
      w2 = ex[e2] * inv;
    }
    int lp1 = 0, lp2 = 0;
#pragma unroll
    for (int e = 0; e < 8; ++e) {
      const unsigned long long m1 = __ballot(e1 == e);
      const unsigned long long m2 = __ballot(e2 == e);
      if (lane == 0) { wc1[wave][e] = __popcll(m1); wc2[wave][e] = __popcll(m2); }
      if (e1 == e) lp1 = __popcll(m1 & lt);
      if (e2 == e) lp2 = __popcll(m2 & lt);
    }
    __syncthreads();
    int r1 = 0, r2 = 0;
    if (t < s) {
      int wp1 = 0, wp2 = 0;
      for (int w = 0; w < wave; ++w) { wp1 += wc1[w][e1]; wp2 += wc2[w][e2]; }
      r1 = base1[e1] + wp1 + lp1;
      r2 = base2[e2] + wp2 + lp2;
    }
    __syncthreads();
    if (tid < 8) {
      int a1 = 0, a2 = 0;
      for (int w = 0; w < ST / 64; ++w) { a1 += wc1[w][tid]; a2 += wc2[w][tid]; }
      base1[tid] += a1;
      base2[tid] += a2;
    }
    __syncthreads();
    e1a[k] = e1; e2a[k] = e2; r1a[k] = r1; r2a[k] = r2; w1a[k] = w1; w2a[k] = w2;
  }

  // base1[e] == tot1[e] (pre-drop top-1 totals, as in the reference).
#pragma unroll
  for (int k = 0; k < ROUNDS; ++k) {
    const int t = k * ST + tid;
    if (t >= s) continue;
    const int p1 = (r1a[k] < cap) ? e1a[k] * cap + r1a[k] : -1;
    const int rr2 = r2a[k] + base1[e2a[k]];
    const int p2 = (rr2 < cap) ? e2a[k] * cap + rr2 : -1;
    float4 rec;
    rec.x = __int_as_float(p1);
    rec.y = w1a[k];
    rec.z = __int_as_float(p2);
    rec.w = w2a[k];
    table[t] = rec;
  }
}

// ONE linear pass over the whole output (both planes). Identical store
// pattern to rocclr fillBuffer (proven 6.24 TB/s on this buffer). Per 16B:
// token = j/row4 (magic-mul when CROW4 compile-time), wave-uniform table
// load (L1 broadcast), embed weight / mask where position matches p1/p2.
template <unsigned CROW4>  // row/4 in float4 units; 0 = runtime
__global__ __launch_bounds__(256) void fused_fill_scatter(
    const float4* __restrict__ table, float4* __restrict__ out,
    unsigned plane4, unsigned row4_rt) {
  const unsigned row4 = CROW4 ? CROW4 : row4_rt;
  unsigned i = blockIdx.x * 256u + threadIdx.x;
  const unsigned stride = gridDim.x * 256u;
  const unsigned total = plane4 * 2u;
  for (; i < total; i += stride) {
    const bool maskplane = (i >= plane4);
    const unsigned j = maskplane ? i - plane4 : i;
    const unsigned t = j / row4;
    const int c0 = (int)((j - t * row4) * 4u);
    const float4 rec = table[t];  // {p1, w1, p2, w2}
    const int p1 = __float_as_int(rec.x);
    const int p2 = __float_as_int(rec.z);
    float4 v = make_float4(0.f, 0.f, 0.f, 0.f);
    float* vp = reinterpret_cast<float*>(&v);
#pragma unroll
    for (int c = 0; c < 4; ++c) {
      const int pos = c0 + c;
      if (pos == p1) vp[c] = maskplane ? ((rec.y != 0.f) ? 1.f : 0.f) : rec.y;
      if (pos == p2) vp[c] = maskplane ? ((rec.w != 0.f) ? 1.f : 0.f) : rec.w;
    }
    out[i] = v;
  }
}

extern "C" void kernel_launch(void* const* d_in, const int* in_sizes, int n_in,
                              void* d_out, int out_size, void* d_ws, size_t ws_size,
                              hipStream_t stream) {
  const float* in = (const float*)d_in[0];
  const int E = 8;
  const int s = in_sizes[0] / E;  // 8192
  int cap = (int)((5LL * s) / (2LL * E));  // floor(2*1.25*s/e)
  cap += cap % 2;
  if (cap < 4) cap = 4;
  const int row = E * cap;            // 20480 floats per token per plane
  const unsigned row4 = row / 4;      // 5120 float4s
  const unsigned plane4 = (unsigned)s * row4;

  float4* table = (float4*)d_ws;  // s * 16B

  // Router first (only depends on d_in); then one pass over the output.
  router_kernel<<<1, ST, 0, stream>>>(in, table, s, cap);
  if (row4 == 5120u) {
    fused_fill_scatter<5120u><<<2048, 256, 0, stream>>>(
        table, (float4*)d_out, plane4, row4);
  } else {
    fused_fill_scatter<0u><<<2048, 256, 0, stream>>>(
        table, (float4*)d_out, plane4, row4);
  }
}